// Round 7
// baseline (223.595 us; speedup 1.0000x reference)
//
#include <hip/hip_runtime.h>

#define IN_CH    16
#define OUT_CH   64
#define SET_LEN  64
#define BB       8
#define HH       56
#define WW       56

#define TILEROWS 8              // output rows per block (56 = 7*8)
#define NTILES   7
#define LDSROWS  (TILEROWS + 2) // staged rows incl. halo
#define LROW     58             // (WW + 2) halo columns
#define LDS_XN   (IN_CH * LDSROWS * LROW)   // 9280 floats = 37120 B

typedef float f32x2 __attribute__((ext_vector_type(2)));
typedef float f32x4 __attribute__((ext_vector_type(4)));

static __device__ __forceinline__ f32x2 splat2(float s) { return (f32x2){s, s}; }

__global__ __launch_bounds__(256, 4)
void rptn_fused_kernel(const float* __restrict__ x,
                       const float* __restrict__ w,
                       const float* __restrict__ bias,
                       const int*   __restrict__ idx,
                       float*       __restrict__ out) {
    const int oc   = blockIdx.x;   // fastest-varying -> x tile reused across oc in L2
    const int tile = blockIdx.y;
    const int b    = blockIdx.z;
    const int tid  = threadIdx.x;
    const int tx   = tid & 63;
    const int grp  = __builtin_amdgcn_readfirstlane(tid >> 6); // wave-uniform

    __shared__ float s_x[LDS_XN];
    __shared__ f32x4 s_w[SET_LEN * 3];       // [64 entries][12 floats]: w0..w8,bias,chan,pad
    __shared__ int   s_cnt[IN_CH];
    __shared__ int   s_pos[IN_CH];
    __shared__ int   s_eord[SET_LEN];

    // ---- counting-sort set entries by source channel (e >> 8) ----
    if (tid < IN_CH) s_cnt[tid] = 0;
    __syncthreads();
    int my_e = 0;
    if (tid < SET_LEN) {
        my_e = idx[oc * SET_LEN + tid];
        atomicAdd(&s_cnt[my_e >> 8], 1);
    }
    __syncthreads();
    if (tid == 0) {
        int run = 0;
        for (int c = 0; c < IN_CH; ++c) { s_pos[c] = run; run += s_cnt[c]; }
    }
    __syncthreads();
    if (tid < SET_LEN) {
        int p = atomicAdd(&s_pos[my_e >> 8], 1);
        s_eord[p] = my_e;
    }
    __syncthreads();   // s_eord ready for the gather below

    // ---- gather sorted weights/bias/channel into LDS table (static offsets later) ----
    float* s_wf = (float*)s_w;
    for (int i = tid; i < SET_LEN * 12; i += 256) {
        const int j    = i / 12;
        const int comp = i - j * 12;
        const int e    = s_eord[j];
        float v;
        if (comp < 9)        v = w[e * 9 + comp];
        else if (comp == 9)  v = bias[e];
        else if (comp == 10) v = __int_as_float(e >> 8);   // channel id as bits
        else                 v = 0.0f;
        s_wf[j * 12 + comp] = v;
    }

    // ---- stage x tile (+halo ring, zero-padded) into LDS; SALU-driven (c,row) ----
    const int r0 = tile * TILEROWS;
    const float* xb = x + (size_t)b * IN_CH * HH * WW;
    const bool lanev = (tx < 56);
    const bool lanew = (tx < 58);
    const int  lcol  = lanev ? (tx + 1) : (tx == 56 ? 0 : 57);
    const int  gcol  = lanev ? tx : 0;
    #pragma unroll
    for (int it = 0; it < (IN_CH * LDSROWS) / 4; ++it) {   // 40 iters/wave
        const int linear = it * 4 + grp;                   // wave-uniform
        const int c  = linear / LDSROWS;
        const int r  = linear - c * LDSROWS;
        const int gr = r0 - 1 + r;
        float v = 0.0f;
        if ((unsigned)gr < (unsigned)HH) {                 // uniform branch
            v = xb[(c * HH + gr) * WW + gcol];
            if (!lanev) v = 0.0f;
        }
        if (lanew) s_x[(c * LDSROWS + r) * LROW + lcol] = v;
    }
    __syncthreads();

    // ---- fused conv + bias + running max; 2 rows per lane, packed fp32 ----
    const int txr = lanev ? tx : 0;          // clamp for safe LDS reads

    f32x2 acc = { -__builtin_inff(), -__builtin_inff() };
    int ccur = -1;
    f32x2 v00={0,0},v01={0,0},v02={0,0};
    f32x2 v10={0,0},v11={0,0},v12={0,0};
    f32x2 v20={0,0},v21={0,0},v22={0,0};

    #pragma unroll 4
    for (int k = 0; k < SET_LEN; ++k) {
        // three 16B-aligned uniform LDS loads at static offsets — no SGPR round-trip
        const f32x4 q0 = s_w[k * 3 + 0];     // w0 w1 w2 w3
        const f32x4 q1 = s_w[k * 3 + 1];     // w4 w5 w6 w7
        const f32x4 q2 = s_w[k * 3 + 2];     // w8 bias chan pad
        const int c = __float_as_int(q2.z);
        if (c != ccur) {                     // wave-uniform branch (~16 of 64 iters)
            ccur = c;
            const float* sp = &s_x[(c * LDSROWS + grp * 2) * LROW + txr];
            const float n00=sp[0],        n01=sp[1],          n02=sp[2];
            const float n10=sp[LROW],     n11=sp[LROW+1],     n12=sp[LROW+2];
            const float n20=sp[2*LROW],   n21=sp[2*LROW+1],   n22=sp[2*LROW+2];
            const float n30=sp[3*LROW],   n31=sp[3*LROW+1],   n32=sp[3*LROW+2];
            v00=(f32x2){n00,n10}; v01=(f32x2){n01,n11}; v02=(f32x2){n02,n12};
            v10=(f32x2){n10,n20}; v11=(f32x2){n11,n21}; v12=(f32x2){n12,n22};
            v20=(f32x2){n20,n30}; v21=(f32x2){n21,n31}; v22=(f32x2){n22,n32};
        }
        f32x2 t0 = __builtin_elementwise_fma(splat2(q0.z), v02,
                   __builtin_elementwise_fma(splat2(q0.y), v01,
                   __builtin_elementwise_fma(splat2(q0.x), v00, splat2(q2.y))));
        f32x2 t1 = __builtin_elementwise_fma(splat2(q1.y), v12,
                   __builtin_elementwise_fma(splat2(q1.x), v11,
                                             splat2(q0.w) * v10));
        f32x2 t2 = __builtin_elementwise_fma(splat2(q2.x), v22,
                   __builtin_elementwise_fma(splat2(q1.w), v21,
                                             splat2(q1.z) * v20));
        acc = __builtin_elementwise_max(acc, t0 + (t1 + t2));
    }

    if (lanev) {
        const size_t o = (((size_t)b * OUT_CH + oc) * HH + (r0 + grp * 2)) * WW + tx;
        out[o]      = acc.x;   // row grp*2
        out[o + WW] = acc.y;   // row grp*2 + 1
    }
}

extern "C" void kernel_launch(void* const* d_in, const int* in_sizes, int n_in,
                              void* d_out, int out_size, void* d_ws, size_t ws_size,
                              hipStream_t stream) {
    const float* x    = (const float*)d_in[0];
    const float* w    = (const float*)d_in[1];
    const float* bias = (const float*)d_in[2];
    const int*   idx  = (const int*)d_in[3];
    float*       out  = (float*)d_out;

    dim3 grid(OUT_CH, NTILES, BB);   // oc fastest -> x tile L2 reuse
    dim3 block(256);
    rptn_fused_kernel<<<grid, block, 0, stream>>>(x, w, bias, idx, out);
}

// Round 8
// 131.636 us; speedup vs baseline: 1.6986x; 1.6986x over previous
//
#include <hip/hip_runtime.h>

#define IN_CH    16
#define OUT_CH   64
#define SET_LEN  64
#define BB       8
#define HH       56
#define WW       56

#define TILEROWS 8              // output rows per block (56 = 7*8)
#define NTILES   7
#define LDSROWS  (TILEROWS + 2) // staged rows incl. halo
#define LROW     60             // 56 data cols + 4 zero cols (right halo + wrap-zero)
#define LDS_XN   (IN_CH * LDSROWS * LROW)   // 9600 floats = 38400 B
#define NVEC     (IN_CH * LDSROWS * 14)     // 2240 float4 transfers

typedef float f32x2 __attribute__((ext_vector_type(2)));
typedef float f32x4 __attribute__((ext_vector_type(4)));

static __device__ __forceinline__ f32x2 splat2(float s) { return (f32x2){s, s}; }

__global__ __launch_bounds__(256, 2)
void rptn_fused_kernel(const float* __restrict__ x,
                       const float* __restrict__ w,
                       const float* __restrict__ bias,
                       const int*   __restrict__ idx,
                       float*       __restrict__ out) {
    const int oc   = blockIdx.x;   // fastest-varying -> x tile reused across oc in L2
    const int tile = blockIdx.y;
    const int b    = blockIdx.z;
    const int tid  = threadIdx.x;
    const int tx   = tid & 63;
    const int grp  = __builtin_amdgcn_readfirstlane(tid >> 6); // wave-uniform

    __shared__ float s_x[LDS_XN];
    __shared__ f32x4 s_w[SET_LEN * 3];   // [64 entries][12 floats]: w0..w8,bias,chan,pad
    __shared__ int   s_cnt[IN_CH];
    __shared__ int   s_pos[IN_CH];
    __shared__ int   s_eord[SET_LEN];

    // ---- counting-sort set entries by source channel (e >> 8) ----
    if (tid < IN_CH) s_cnt[tid] = 0;
    __syncthreads();
    int my_e = 0;
    if (tid < SET_LEN) {
        my_e = idx[oc * SET_LEN + tid];
        atomicAdd(&s_cnt[my_e >> 8], 1);
    }
    __syncthreads();
    if (tid == 0) {
        int run = 0;
        for (int c = 0; c < IN_CH; ++c) { s_pos[c] = run; run += s_cnt[c]; }
    }
    __syncthreads();
    if (tid < SET_LEN) {
        int p = atomicAdd(&s_pos[my_e >> 8], 1);
        s_eord[p] = my_e;
    }
    __syncthreads();   // s_eord final before table gather

    // ---- gather sorted weights/bias/channel into LDS table ----
    float* s_wf = (float*)s_w;
    for (int i = tid; i < SET_LEN * 12; i += 256) {
        const int j    = i / 12;
        const int comp = i - j * 12;
        const int e    = s_eord[j];
        float v;
        if (comp < 9)        v = w[e * 9 + comp];
        else if (comp == 9)  v = bias[e];
        else if (comp == 10) v = __int_as_float(e >> 8);   // channel id as bits
        else                 v = 0.0f;
        s_wf[j * 12 + comp] = v;
    }

    // ---- stage x tile: aligned vec4 loads + vec4 LDS writes, fully pipelined ----
    // row layout: cols 0..55 = data, cols 56..59 = zero (right halo; col 57 doubles
    // as the left-neighbor "zero" for col 0 via index wrap).
    const int r0 = tile * TILEROWS;
    const float* xb = x + (size_t)b * IN_CH * HH * WW;
    {
        // zero columns 56..59 of each of the 160 rows
        if (tid < IN_CH * LDSROWS) {
            *(f32x4*)&s_x[tid * LROW + 56] = (f32x4){0, 0, 0, 0};
        }
        // interior: 2240 aligned vec4 transfers, 8 full rounds + tail
        #pragma unroll
        for (int it = 0; it < 9; ++it) {
            const int v = tid + it * 256;
            if (it < 8 || v < NVEC) {                  // last round: tid<192
                const int c   = v / (LDSROWS * 14);
                const int rem = v - c * (LDSROWS * 14);
                const int r   = rem / 14;
                const int q   = rem - r * 14;
                const int gr  = r0 - 1 + r;
                f32x4 val = {0, 0, 0, 0};
                if ((unsigned)gr < (unsigned)HH)
                    val = *(const f32x4*)(xb + (c * HH + gr) * WW + q * 4);
                *(f32x4*)&s_x[(c * LDSROWS + r) * LROW + q * 4] = val;
            }
        }
    }
    __syncthreads();

    // ---- fused conv + bias + running max; 2 rows per lane, packed fp32 ----
    const bool lanev = (tx < WW);
    const int  txr   = lanev ? tx : 0;            // clamp for safe LDS reads
    const int  txl   = (txr == 0) ? 57 : txr - 1; // left neighbor (col 57 is zero)

    f32x2 acc = { -__builtin_inff(), -__builtin_inff() };
    int ccur = -1;
    f32x2 v00={0,0},v01={0,0},v02={0,0};
    f32x2 v10={0,0},v11={0,0},v12={0,0};
    f32x2 v20={0,0},v21={0,0},v22={0,0};

    #pragma unroll 2
    for (int k = 0; k < SET_LEN; ++k) {
        // three uniform 16B LDS loads at static offsets (broadcast, no SGPR trip)
        const f32x4 q0 = s_w[k * 3 + 0];     // w0 w1 w2 w3
        const f32x4 q1 = s_w[k * 3 + 1];     // w4 w5 w6 w7
        const f32x4 q2 = s_w[k * 3 + 2];     // w8 bias chan pad
        const int c = __float_as_int(q2.z);
        if (c != ccur) {                     // wave-uniform branch (~16 of 64 iters)
            ccur = c;
            const float* sp = &s_x[(c * LDSROWS + grp * 2) * LROW];
            const float n00=sp[txl],        n01=sp[txr],        n02=sp[txr+1];
            const float n10=sp[LROW+txl],   n11=sp[LROW+txr],   n12=sp[LROW+txr+1];
            const float n20=sp[2*LROW+txl], n21=sp[2*LROW+txr], n22=sp[2*LROW+txr+1];
            const float n30=sp[3*LROW+txl], n31=sp[3*LROW+txr], n32=sp[3*LROW+txr+1];
            v00=(f32x2){n00,n10}; v01=(f32x2){n01,n11}; v02=(f32x2){n02,n12};
            v10=(f32x2){n10,n20}; v11=(f32x2){n11,n21}; v12=(f32x2){n12,n22};
            v20=(f32x2){n20,n30}; v21=(f32x2){n21,n31}; v22=(f32x2){n22,n32};
        }
        f32x2 t0 = __builtin_elementwise_fma(splat2(q0.z), v02,
                   __builtin_elementwise_fma(splat2(q0.y), v01,
                   __builtin_elementwise_fma(splat2(q0.x), v00, splat2(q2.y))));
        f32x2 t1 = __builtin_elementwise_fma(splat2(q1.y), v12,
                   __builtin_elementwise_fma(splat2(q1.x), v11,
                                             splat2(q0.w) * v10));
        f32x2 t2 = __builtin_elementwise_fma(splat2(q2.x), v22,
                   __builtin_elementwise_fma(splat2(q1.w), v21,
                                             splat2(q1.z) * v20));
        acc = __builtin_elementwise_max(acc, t0 + (t1 + t2));
    }

    if (lanev) {
        const size_t o = (((size_t)b * OUT_CH + oc) * HH + (r0 + grp * 2)) * WW + tx;
        out[o]      = acc.x;   // row grp*2
        out[o + WW] = acc.y;   // row grp*2 + 1
    }
}

extern "C" void kernel_launch(void* const* d_in, const int* in_sizes, int n_in,
                              void* d_out, int out_size, void* d_ws, size_t ws_size,
                              hipStream_t stream) {
    const float* x    = (const float*)d_in[0];
    const float* w    = (const float*)d_in[1];
    const float* bias = (const float*)d_in[2];
    const int*   idx  = (const int*)d_in[3];
    float*       out  = (float*)d_out;

    dim3 grid(OUT_CH, NTILES, BB);   // oc fastest -> x tile L2 reuse
    dim3 block(256);
    rptn_fused_kernel<<<grid, block, 0, stream>>>(x, w, bias, idx, out);
}

// Round 9
// 122.769 us; speedup vs baseline: 1.8213x; 1.0722x over previous
//
#include <hip/hip_runtime.h>

#define IN_CH    16
#define OUT_CH   64
#define SET_LEN  64
#define BB       8
#define HH       56
#define WW       56

#define TILEROWS 8              // output rows per block (56 = 7*8)
#define NTILES   7
#define LDSROWS  (TILEROWS + 2) // staged rows incl. halo
#define LROW     56             // exactly the data columns; 224B row stride (16B-aligned)
#define LDS_XN   (IN_CH * LDSROWS * LROW)   // 8960 floats = 35840 B
#define NVEC     (IN_CH * LDSROWS * 14)     // 2240 float4 transfers

typedef float f32x2 __attribute__((ext_vector_type(2)));
typedef float f32x4 __attribute__((ext_vector_type(4)));

static __device__ __forceinline__ f32x2 splat2(float s) { return (f32x2){s, s}; }

__global__ __launch_bounds__(256, 2)
void rptn_fused_kernel(const float* __restrict__ x,
                       const float* __restrict__ w,
                       const float* __restrict__ bias,
                       const int*   __restrict__ idx,
                       float*       __restrict__ out) {
    const int oc   = blockIdx.x;   // fastest-varying -> x tile reused across oc in L2
    const int tile = blockIdx.y;
    const int b    = blockIdx.z;
    const int tid  = threadIdx.x;
    const int tx   = tid & 63;
    const int grp  = __builtin_amdgcn_readfirstlane(tid >> 6); // wave-uniform

    __shared__ float s_x[LDS_XN];
    __shared__ f32x4 s_w[SET_LEN * 3];   // [64 entries][12 floats]: w0..w8,bias,chan,pad
    __shared__ int   s_cnt[IN_CH];
    __shared__ int   s_pos[IN_CH];
    __shared__ int   s_eord[SET_LEN];

    // ---- counting-sort set entries by source channel (e >> 8) ----
    if (tid < IN_CH) s_cnt[tid] = 0;
    __syncthreads();
    int my_e = 0;
    if (tid < SET_LEN) {
        my_e = idx[oc * SET_LEN + tid];
        atomicAdd(&s_cnt[my_e >> 8], 1);
    }
    __syncthreads();
    if (tid == 0) {
        int run = 0;
        for (int c = 0; c < IN_CH; ++c) { s_pos[c] = run; run += s_cnt[c]; }
    }
    __syncthreads();
    if (tid < SET_LEN) {
        int p = atomicAdd(&s_pos[my_e >> 8], 1);
        s_eord[p] = my_e;
    }
    __syncthreads();   // s_eord final before table gather

    // ---- gather sorted weights/bias/channel into LDS table ----
    float* s_wf = (float*)s_w;
    for (int i = tid; i < SET_LEN * 12; i += 256) {
        const int j    = i / 12;
        const int comp = i - j * 12;
        const int e    = s_eord[j];
        float v;
        if (comp < 9)        v = w[e * 9 + comp];
        else if (comp == 9)  v = bias[e];
        else if (comp == 10) v = __int_as_float(e >> 8);   // channel id as bits
        else                 v = 0.0f;
        s_wf[j * 12 + comp] = v;
    }

    // ---- stage x tile: aligned vec4 loads + vec4 LDS writes, fully pipelined ----
    const int r0 = tile * TILEROWS;
    const float* xb = x + (size_t)b * IN_CH * HH * WW;
    #pragma unroll
    for (int it = 0; it < 9; ++it) {
        const int v = tid + it * 256;
        if (it < 8 || v < NVEC) {                  // last round: tid<192
            const int c   = v / (LDSROWS * 14);
            const int rem = v - c * (LDSROWS * 14);
            const int r   = rem / 14;
            const int q   = rem - r * 14;
            const int gr  = r0 - 1 + r;
            f32x4 val = {0, 0, 0, 0};
            if ((unsigned)gr < (unsigned)HH)
                val = *(const f32x4*)(xb + (c * HH + gr) * WW + q * 4);
            *(f32x4*)&s_x[(c * LDSROWS + r) * LROW + q * 4] = val;
        }
    }
    __syncthreads();

    // ---- fused conv + bias + running max; 2 rows per lane, packed fp32 ----
    const bool  lanev = (tx < WW);
    const int   txr   = lanev ? tx : 0;            // clamp for safe LDS reads
    const int   txl   = (txr > 0)  ? txr - 1 : 0;  // in-row clamp; masked by lm
    const int   txp   = (txr < 55) ? txr + 1 : 55; // in-row clamp; masked by rm
    const float lm    = (txr == 0)  ? 0.0f : 1.0f; // left-edge tap mask
    const float rm    = (txr == 55) ? 0.0f : 1.0f; // right-edge tap mask

    f32x2 acc = { -__builtin_inff(), -__builtin_inff() };
    int ccur = -1;
    f32x2 v00={0,0},v01={0,0},v02={0,0};
    f32x2 v10={0,0},v11={0,0},v12={0,0};
    f32x2 v20={0,0},v21={0,0},v22={0,0};

    #pragma unroll 2
    for (int k = 0; k < SET_LEN; ++k) {
        // three uniform 16B LDS loads at static offsets (broadcast, no SGPR trip)
        const f32x4 q0 = s_w[k * 3 + 0];     // w0 w1 w2 w3
        const f32x4 q1 = s_w[k * 3 + 1];     // w4 w5 w6 w7
        const f32x4 q2 = s_w[k * 3 + 2];     // w8 bias chan pad
        const int c = __float_as_int(q2.z);
        if (c != ccur) {                     // wave-uniform branch (~16 of 64 iters)
            ccur = c;
            const float* sp = &s_x[(c * LDSROWS + grp * 2) * LROW];
            const float n00=sp[txl]*lm,        n01=sp[txr],        n02=sp[txp]*rm;
            const float n10=sp[LROW+txl]*lm,   n11=sp[LROW+txr],   n12=sp[LROW+txp]*rm;
            const float n20=sp[2*LROW+txl]*lm, n21=sp[2*LROW+txr], n22=sp[2*LROW+txp]*rm;
            const float n30=sp[3*LROW+txl]*lm, n31=sp[3*LROW+txr], n32=sp[3*LROW+txp]*rm;
            v00=(f32x2){n00,n10}; v01=(f32x2){n01,n11}; v02=(f32x2){n02,n12};
            v10=(f32x2){n10,n20}; v11=(f32x2){n11,n21}; v12=(f32x2){n12,n22};
            v20=(f32x2){n20,n30}; v21=(f32x2){n21,n31}; v22=(f32x2){n22,n32};
        }
        f32x2 t0 = __builtin_elementwise_fma(splat2(q0.z), v02,
                   __builtin_elementwise_fma(splat2(q0.y), v01,
                   __builtin_elementwise_fma(splat2(q0.x), v00, splat2(q2.y))));
        f32x2 t1 = __builtin_elementwise_fma(splat2(q1.y), v12,
                   __builtin_elementwise_fma(splat2(q1.x), v11,
                                             splat2(q0.w) * v10));
        f32x2 t2 = __builtin_elementwise_fma(splat2(q2.x), v22,
                   __builtin_elementwise_fma(splat2(q1.w), v21,
                                             splat2(q1.z) * v20));
        const f32x2 s = t0 + (t1 + t2);
        acc.x = fmaxf(acc.x, s.x);           // scalar max (no v_pk_max_f32)
        acc.y = fmaxf(acc.y, s.y);
    }

    if (lanev) {
        const size_t o = (((size_t)b * OUT_CH + oc) * HH + (r0 + grp * 2)) * WW + tx;
        out[o]      = acc.x;   // row grp*2
        out[o + WW] = acc.y;   // row grp*2 + 1
    }
}

extern "C" void kernel_launch(void* const* d_in, const int* in_sizes, int n_in,
                              void* d_out, int out_size, void* d_ws, size_t ws_size,
                              hipStream_t stream) {
    const float* x    = (const float*)d_in[0];
    const float* w    = (const float*)d_in[1];
    const float* bias = (const float*)d_in[2];
    const int*   idx  = (const int*)d_in[3];
    float*       out  = (float*)d_out;

    dim3 grid(OUT_CH, NTILES, BB);   // oc fastest -> x tile L2 reuse
    dim3 block(256);
    rptn_fused_kernel<<<grid, block, 0, stream>>>(x, w, bias, idx, out);
}